// Round 11
// baseline (7362.792 us; speedup 1.0000x reference)
//
#include <hip/hip_runtime.h>
#include <stdint.h>
#include <stddef.h>

// Persistent 2-layer LSTM, V11: tag-embedded publishes (self-validating data,
// NO flags). Each h value is published as u32 = (step_tag<<16)|bf16; consumers
// poll their own data chunks until tags match -> the data load IS the sync
// (one RT leg instead of flag-RT + data-RT). Publishes are fire-and-forget,
// deferred to the top of the next round (acks overlap staging loads).
// 2 barriers/step (was 5). Ring safety: buf1 depth 4, buf2 depth 2; the
// tag-poll chain guarantees every overwritten slot was already consumed.
// B=128,T=512,D=128,H=512. 8 clusters x 32 blocks; block owns 16 h-cols of
// both layers; 4 waves = 4 K-quarters; 1 block/CU (~87KB LDS).

typedef __attribute__((ext_vector_type(8))) short short8;
typedef __attribute__((ext_vector_type(4))) float f32x4;
typedef unsigned long long u64;

#define DEV static __device__ __forceinline__
#define SCOPE_AGENT __HIP_MEMORY_SCOPE_AGENT

constexpr int TSEQ = 512;
constexpr int DIN  = 128;
constexpr int HDIM = 512;
constexpr int NCL  = 8;    // clusters (bid&7; perf-only placement heuristic)
constexpr int BB   = 16;   // batch rows per cluster
constexpr int COLS = 16;   // h-cols per block

constexpr u64 TAGMASK = 0xFFFF0000FFFF0000ULL;

DEV unsigned short f2bf(float f) {
  unsigned u = __float_as_uint(f);
  u += 0x7fffu + ((u >> 16) & 1u);   // RNE
  return (unsigned short)(u >> 16);
}
DEV short8 pack8(float4 a, float4 b) {
  short8 r;
  r[0] = (short)f2bf(a.x); r[1] = (short)f2bf(a.y);
  r[2] = (short)f2bf(a.z); r[3] = (short)f2bf(a.w);
  r[4] = (short)f2bf(b.x); r[5] = (short)f2bf(b.y);
  r[6] = (short)f2bf(b.z); r[7] = (short)f2bf(b.w);
  return r;
}
DEV f32x4 mfma16(short8 a, short8 b, f32x4 c) {
  return __builtin_amdgcn_mfma_f32_16x16x32_bf16(a, b, c, 0, 0, 0);
}
DEV float sigf(float v) { return 1.f / (1.f + __expf(-v)); }
DEV float tanh_(float v) {
  v = fminf(20.f, fmaxf(-20.f, v));
  float e = __expf(2.f * v);
  return (e - 1.f) / (e + 1.f);
}

__global__ void zero_ws(unsigned* p, int n) {
  int i = blockIdx.x * 256 + threadIdx.x;
  if (i < n)
    __hip_atomic_store(p + i, 0u, __ATOMIC_RELAXED, SCOPE_AGENT);
}

// LDS slab swizzle on short-index: byte ^ ((row&15)<<4)
#define SWZ(row, idx) ((idx) ^ (((row) & 15) << 3))

// Poll-stage one 16-row x 512-col tagged slab chunk into swizzled LDS.
// Thread covers 32 consecutive u32 at (row, colb..colb+31): 16 u64 loads,
// validate all tags == tag (loop until true), strip tags, write 8B granules.
DEV void stage_slab(short* lds, const unsigned* src, unsigned tag,
                    int row, int colb) {
  const u64 expv = ((u64)tag << 16) | ((u64)tag << 48);
  const unsigned* base = src + row * HDIM + colb;
  u64 t[16];
  while (true) {
    #pragma unroll
    for (int c = 0; c < 8; ++c) {
      const u64* s = (const u64*)(base + c * 4);
      t[2 * c]     = __hip_atomic_load(s,     __ATOMIC_RELAXED, SCOPE_AGENT);
      t[2 * c + 1] = __hip_atomic_load(s + 1, __ATOMIC_RELAXED, SCOPE_AGENT);
    }
    u64 d = 0;
    #pragma unroll
    for (int c = 0; c < 16; ++c) d |= (t[c] ^ expv) & TAGMASK;
    if (d == 0) break;
    __builtin_amdgcn_s_sleep(1);
  }
  #pragma unroll
  for (int c = 0; c < 8; ++c) {
    const u64 lo = t[2 * c], hi = t[2 * c + 1];
    const u64 v = (lo & 0xFFFFull) | ((lo >> 16) & 0xFFFF0000ull)
                | ((hi & 0xFFFFull) << 32) | (((hi >> 16) & 0xFFFF0000ull) << 32);
    const int f = row * HDIM + colb + c * 4;
    *(u64*)&lds[SWZ(row, f)] = v;
  }
}

__global__ __launch_bounds__(256, 1) void lstm_persist(
    const float* __restrict__ x,
    const float* __restrict__ Wih1, const float* __restrict__ Whh1,
    const float* __restrict__ bih1, const float* __restrict__ bhh1,
    const float* __restrict__ Wih2, const float* __restrict__ Whh2,
    const float* __restrict__ bih2, const float* __restrict__ bhh2,
    float* __restrict__ out,
    unsigned* __restrict__ buf1,   // [4][NCL][BB][HDIM] u32 tagged h1/out1 ring
    unsigned* __restrict__ buf2)   // [2][NCL][BB][HDIM] u32 tagged h2 ring
{
  __shared__ short xs [16 * DIN];    // 4KB   x_t (bf16, swizzled)
  __shared__ short h1s[16 * HDIM];   // 16KB  h1_{it-1}
  __shared__ short o1s[16 * HDIM];   // 16KB  out1_{it-3}
  __shared__ short h2s[16 * HDIM];   // 16KB  h2_{it-4}
  __shared__ float red1[4 * 16 * 66];
  __shared__ float red2[4 * 16 * 66];
  __shared__ float bias1s[64], bias2s[64];

  const int tid  = threadIdx.x;
  const int lane = tid & 63;
  const int lm   = lane & 15;   // A row (batch row) / C col index
  const int lq   = lane >> 4;   // k-octet / C row group
  const int kq   = tid >> 6;    // wave = K-quarter

  const int bid     = blockIdx.x;
  const int cluster = bid & 7;
  const int j       = bid >> 3;       // 0..31 col-group within cluster
  const int cb      = cluster * BB;   // global batch base

  // ---- persistent register weights: B-fragments, n = lane&15 -> gate row ----
  short8 wf1[4][5];   // layer1: K=640 -> 20 K-steps, 5 per wave, x4 gates
  short8 wf2[4][8];   // layer2: K=1024 -> 32 K-steps, 8 per wave, x4 gates
  #pragma unroll
  for (int g = 0; g < 4; ++g) {
    const int gr = g * HDIM + j * COLS + lm;
    #pragma unroll
    for (int sl = 0; sl < 5; ++sl) {
      const int k0 = (kq * 5 + sl) * 32 + 8 * lq;          // 0..639
      const float* src = (k0 < DIN) ? (Wih1 + (size_t)gr * DIN + k0)
                                    : (Whh1 + (size_t)gr * HDIM + (k0 - DIN));
      wf1[g][sl] = pack8(*(const float4*)src, *(const float4*)(src + 4));
    }
    #pragma unroll
    for (int sl = 0; sl < 8; ++sl) {
      const int k0 = (kq * 8 + sl) * 32 + 8 * lq;          // 0..1023
      const float* src = (k0 < HDIM) ? (Wih2 + (size_t)gr * HDIM + k0)
                                     : (Whh2 + (size_t)gr * HDIM + (k0 - HDIM));
      wf2[g][sl] = pack8(*(const float4*)src, *(const float4*)(src + 4));
    }
  }
  if (tid < 64) {
    const int g = tid >> 4, nn = tid & 15;
    const int gr = g * HDIM + j * COLS + nn;
    bias1s[tid] = bih1[gr] + bhh1[gr];
    bias2s[tid] = bih2[gr] + bhh2[gr];
  }

  // pickup: thread = (batch row pm, col pnn); owns c1,c2 across all steps
  const int pm = tid >> 4, pnn = tid & 15;
  float c1 = 0.f, c2 = 0.f;
  unsigned short h1w = 0, h2w = 0;   // held publish values (stored next round)

  // staging map: thread covers (srow, scolb..scolb+31)
  const int srow  = tid >> 4;
  const int scolb = (tid & 15) * 32;

  for (int it = 0; it <= TSEQ + 2; ++it) {
    const bool l1 = (it < TSEQ);
    const bool l2 = (it >= 3);          // processes t2 = it-3
    const int  t2 = it - 3;

    // ---- publish previous round's results (fire-and-forget, tagged) ----
    if (it >= 1 && it <= TSEQ) {        // h1_{it-1}, tag = it
      unsigned* wp = buf1 + (size_t)((((it - 1) & 3) * NCL + cluster) * BB) * HDIM;
      __hip_atomic_store(&wp[pm * HDIM + j * COLS + pnn],
                         (unsigned)h1w | ((unsigned)it << 16),
                         __ATOMIC_RELAXED, SCOPE_AGENT);
    }
    if (it >= 4 && it - 4 <= 510) {     // h2_{it-4}, tag = it-3
      unsigned* wp = buf2 + (size_t)((((it - 4) & 1) * NCL + cluster) * BB) * HDIM;
      __hip_atomic_store(&wp[pm * HDIM + j * COLS + pnn],
                         (unsigned)h2w | ((unsigned)(it - 3) << 16),
                         __ATOMIC_RELAXED, SCOPE_AGENT);
    }

    // ---- x load (HBM/L3, independent) ----
    float4 xa, xb;
    if (l1) {
      const float* xp = x + ((size_t)(cb + srow) * TSEQ + it) * DIN + (tid & 15) * 8;
      xa = *(const float4*)xp; xb = *(const float4*)(xp + 4);
    }

    // ---- staged, tag-validated loads (o1/h2 resolve instantly; h1 polls) ----
    if (l2) {
      const unsigned* o1r =
          buf1 + (size_t)(((t2 & 3) * NCL + cluster) * BB) * HDIM;
      stage_slab(o1s, o1r, (unsigned)(it - 2), srow, scolb);   // out1_{it-3}
      const unsigned* h2r =
          buf2 + (size_t)((((it - 4) & 1) * NCL + cluster) * BB) * HDIM;
      stage_slab(h2s, h2r, (unsigned)(it - 3), srow, scolb);   // h2_{it-4}
    }
    if (l1) {
      const unsigned* h1r =
          buf1 + (size_t)((((it - 1) & 3) * NCL + cluster) * BB) * HDIM;
      stage_slab(h1s, h1r, (unsigned)it, srow, scolb);         // h1_{it-1}
      *(short8*)(&xs[SWZ(srow, srow * DIN + (tid & 15) * 8)]) = pack8(xa, xb);
    }
    __syncthreads();   // sync_A: slabs ready (also fences prior red reads)

    // ---- MFMA: wave kq does its K-quarter, all 4 gate N-tiles ----
    if (l1) {
      f32x4 z = {0.f, 0.f, 0.f, 0.f};
      f32x4 acc1[4] = {z, z, z, z};
      #pragma unroll
      for (int sl = 0; sl < 5; ++sl) {
        const int s = kq * 5 + sl;       // K = [x(4) | h1(16)] K-steps
        short8 a;
        if (s < 4)   // only kq==0
          a = *(const short8*)(&xs[SWZ(lm, lm * DIN + s * 32 + 8 * lq)]);
        else
          a = *(const short8*)(&h1s[SWZ(lm, lm * HDIM + (s - 4) * 32 + 8 * lq)]);
        #pragma unroll
        for (int g = 0; g < 4; ++g) acc1[g] = mfma16(a, wf1[g][sl], acc1[g]);
      }
      #pragma unroll
      for (int g = 0; g < 4; ++g)
        #pragma unroll
        for (int r = 0; r < 4; ++r)
          red1[(kq * 16 + lq * 4 + r) * 66 + g * 16 + lm] = acc1[g][r];
    }
    if (l2) {
      f32x4 z = {0.f, 0.f, 0.f, 0.f};
      f32x4 acc2[4] = {z, z, z, z};
      #pragma unroll
      for (int sl = 0; sl < 8; ++sl) {
        const int s2 = kq * 8 + sl;      // K = [out1(16) | h2(16)] K-steps
        short8 a;
        if (s2 < 16)
          a = *(const short8*)(&o1s[SWZ(lm, lm * HDIM + s2 * 32 + 8 * lq)]);
        else
          a = *(const short8*)(&h2s[SWZ(lm, lm * HDIM + (s2 - 16) * 32 + 8 * lq)]);
        #pragma unroll
        for (int g = 0; g < 4; ++g) acc2[g] = mfma16(a, wf2[g][sl], acc2[g]);
      }
      #pragma unroll
      for (int g = 0; g < 4; ++g)
        #pragma unroll
        for (int r = 0; r < 4; ++r)
          red2[(kq * 16 + lq * 4 + r) * 66 + g * 16 + lm] = acc2[g][r];
    }
    __syncthreads();   // sync_B: red complete

    // ---- pickup (results held in regs; published at next round's top) ----
    if (l1) {
      float p[4];
      #pragma unroll
      for (int g = 0; g < 4; ++g) {
        float v = bias1s[g * 16 + pnn];
        #pragma unroll
        for (int q = 0; q < 4; ++q) v += red1[(q * 16 + pm) * 66 + g * 16 + pnn];
        p[g] = v;
      }
      const float i_ = sigf(p[0]), f_ = sigf(p[1]);
      const float g_ = tanh_(p[2]), o_ = sigf(p[3]);
      c1 = f_ * c1 + i_ * g_;
      h1w = f2bf(o_ * tanh_(c1));
    }
    if (l2) {
      float p[4];
      #pragma unroll
      for (int g = 0; g < 4; ++g) {
        float v = bias2s[g * 16 + pnn];
        #pragma unroll
        for (int q = 0; q < 4; ++q) v += red2[(q * 16 + pm) * 66 + g * 16 + pnn];
        p[g] = v;
      }
      const float i_ = sigf(p[0]), f_ = sigf(p[1]);
      const float g_ = tanh_(p[2]), o_ = sigf(p[3]);
      c2 = f_ * c2 + i_ * g_;
      const float h2v = o_ * tanh_(c2);
      if (t2 < TSEQ - 1) {
        h2w = f2bf(h2v);
      } else {                            // final states (t2 = 511)
        const int b = cb + pm;
        out[(size_t)b * HDIM + j * COLS + pnn] = h2v;
        out[(size_t)128 * HDIM + (size_t)b * HDIM + j * COLS + pnn] = c2;
      }
    }
    // no barrier here: next round's sync_A orders red reads vs next writes
  }
}

extern "C" void kernel_launch(void* const* d_in, const int* in_sizes, int n_in,
                              void* d_out, int out_size, void* d_ws, size_t ws_size,
                              hipStream_t stream) {
  const float* x    = (const float*)d_in[0];
  const float* Wih1 = (const float*)d_in[1];
  const float* Whh1 = (const float*)d_in[2];
  const float* bih1 = (const float*)d_in[3];
  const float* bhh1 = (const float*)d_in[4];
  const float* Wih2 = (const float*)d_in[5];
  const float* Whh2 = (const float*)d_in[6];
  const float* bih2 = (const float*)d_in[7];
  const float* bhh2 = (const float*)d_in[8];
  float* out = (float*)d_out;

  const size_t buf1Elems = (size_t)4 * NCL * BB * HDIM;   // 262144 u32 (1MB)
  const size_t buf2Elems = (size_t)2 * NCL * BB * HDIM;   // 131072 u32 (0.5MB)
  unsigned* buf1 = (unsigned*)d_ws;
  unsigned* buf2 = buf1 + buf1Elems;

  const int nzero = (int)(buf1Elems + buf2Elems);         // u32 words
  zero_ws<<<(nzero + 255) / 256, 256, 0, stream>>>((unsigned*)d_ws, nzero);
  lstm_persist<<<256, 256, 0, stream>>>(x, Wih1, Whh1, bih1, bhh1,
                                        Wih2, Whh2, bih2, bhh2,
                                        out, buf1, buf2);
}

// Round 12
// 2348.683 us; speedup vs baseline: 3.1349x; 3.1349x over previous
//
#include <hip/hip_runtime.h>
#include <stdint.h>
#include <stddef.h>

// Persistent 2-layer LSTM, V12: V10 schedule + lean-tail protocol.
// - ONE flag per block (flag=k <=> round k-1 done); single poll target.
// - Pickups write h1/h2 into a 512B LDS pub buffer; wave 0 alone publishes
//   both as coalesced 8B agent stores, wave-local vmcnt(0), then the flag.
//   (Removes both full-block post-publish barriers/drains of V6/V10.)
// - Merged MFMA/red/pickup phases: 4 __syncthreads per round (was 6).
// B=128,T=512,D=128,H=512. 8 clusters x 32 blocks; block owns 16 h-cols of
// both layers; 4 waves = 4 K-quarters; 1 block/CU (~88KB LDS).

typedef __attribute__((ext_vector_type(8))) short short8;
typedef __attribute__((ext_vector_type(4))) float f32x4;
typedef unsigned long long u64;

#define DEV static __device__ __forceinline__
#define SCOPE_AGENT __HIP_MEMORY_SCOPE_AGENT

constexpr int TSEQ = 512;
constexpr int DIN  = 128;
constexpr int HDIM = 512;
constexpr int NCL  = 8;    // clusters (bid&7; perf-only placement heuristic)
constexpr int BB   = 16;   // batch rows per cluster
constexpr int COLS = 16;   // h-cols per block

DEV unsigned short f2bf(float f) {
  unsigned u = __float_as_uint(f);
  u += 0x7fffu + ((u >> 16) & 1u);   // RNE
  return (unsigned short)(u >> 16);
}
DEV short8 pack8(float4 a, float4 b) {
  short8 r;
  r[0] = (short)f2bf(a.x); r[1] = (short)f2bf(a.y);
  r[2] = (short)f2bf(a.z); r[3] = (short)f2bf(a.w);
  r[4] = (short)f2bf(b.x); r[5] = (short)f2bf(b.y);
  r[6] = (short)f2bf(b.z); r[7] = (short)f2bf(b.w);
  return r;
}
DEV short8 mk8(u64 lo, u64 hi) {
  union { u64 q[2]; short8 v; } u;
  u.q[0] = lo; u.q[1] = hi; return u.v;
}
DEV f32x4 mfma16(short8 a, short8 b, f32x4 c) {
  return __builtin_amdgcn_mfma_f32_16x16x32_bf16(a, b, c, 0, 0, 0);
}
DEV float sigf(float v) { return 1.f / (1.f + __expf(-v)); }
DEV float tanh_(float v) {
  v = fminf(20.f, fmaxf(-20.f, v));
  float e = __expf(2.f * v);
  return (e - 1.f) / (e + 1.f);
}

__global__ void zero_ws(unsigned* p, int n) {
  int i = blockIdx.x * 256 + threadIdx.x;
  if (i < n)
    __hip_atomic_store(p + i, 0u, __ATOMIC_RELAXED, SCOPE_AGENT);
}

// LDS slab swizzle on short-index: byte ^ ((row&15)<<4)
#define SWZ(row, idx) ((idx) ^ (((row) & 15) << 3))

__global__ __launch_bounds__(256, 1) void lstm_persist(
    const float* __restrict__ x,
    const float* __restrict__ Wih1, const float* __restrict__ Whh1,
    const float* __restrict__ bih1, const float* __restrict__ bhh1,
    const float* __restrict__ Wih2, const float* __restrict__ Whh2,
    const float* __restrict__ bih2, const float* __restrict__ bhh2,
    float* __restrict__ out,
    unsigned short* __restrict__ buf1,   // [4][NCL][BB][HDIM] bf16 h1/out1 ring
    unsigned short* __restrict__ buf2,   // [2][NCL][BB][HDIM] bf16 h2 ring
    unsigned* __restrict__ flags)        // [NCL][32] single flag per block
{
  __shared__ short xs [16 * DIN];    // 4KB   x_t (bf16, swizzled)
  __shared__ short h1s[16 * HDIM];   // 16KB  h1_{it-1}
  __shared__ short o1s[16 * HDIM];   // 16KB  out1_{it-3}
  __shared__ short h2s[16 * HDIM];   // 16KB  h2_{it-4}
  __shared__ float red1[4 * 16 * 66];
  __shared__ float red2[4 * 16 * 66];
  __shared__ float bias1s[64], bias2s[64];
  __shared__ unsigned short pub1s[256], pub2s[256];   // publish staging

  const int tid  = threadIdx.x;
  const int lane = tid & 63;
  const int lm   = lane & 15;   // A row (batch row) / C col index
  const int lq   = lane >> 4;   // k-octet / C row group
  const int kq   = tid >> 6;    // wave = K-quarter

  const int bid     = blockIdx.x;
  const int cluster = bid & 7;
  const int j       = bid >> 3;       // 0..31 col-group within cluster
  const int cb      = cluster * BB;   // global batch base
  unsigned* flag = flags + cluster * 32;   // flag=k <=> round k-1 done

  // ---- persistent register weights: B-fragments, n = lane&15 -> gate row ----
  short8 wf1[4][5];   // layer1: K=640 -> 20 K-steps, 5 per wave, x4 gates
  short8 wf2[4][8];   // layer2: K=1024 -> 32 K-steps, 8 per wave, x4 gates
  #pragma unroll
  for (int g = 0; g < 4; ++g) {
    const int gr = g * HDIM + j * COLS + lm;
    #pragma unroll
    for (int sl = 0; sl < 5; ++sl) {
      const int k0 = (kq * 5 + sl) * 32 + 8 * lq;          // 0..639
      const float* src = (k0 < DIN) ? (Wih1 + (size_t)gr * DIN + k0)
                                    : (Whh1 + (size_t)gr * HDIM + (k0 - DIN));
      wf1[g][sl] = pack8(*(const float4*)src, *(const float4*)(src + 4));
    }
    #pragma unroll
    for (int sl = 0; sl < 8; ++sl) {
      const int k0 = (kq * 8 + sl) * 32 + 8 * lq;          // 0..1023
      const float* src = (k0 < HDIM) ? (Wih2 + (size_t)gr * HDIM + k0)
                                     : (Whh2 + (size_t)gr * HDIM + (k0 - HDIM));
      wf2[g][sl] = pack8(*(const float4*)src, *(const float4*)(src + 4));
    }
  }
  if (tid < 64) {
    const int g = tid >> 4, nn = tid & 15;
    const int gr = g * HDIM + j * COLS + nn;
    bias1s[tid] = bih1[gr] + bhh1[gr];
    bias2s[tid] = bih2[gr] + bhh2[gr];
  }

  // pickup: thread = (batch row pm, col pnn); owns c1,c2 across all steps
  const int pm = tid >> 4, pnn = tid & 15;
  float c1 = 0.f, c2 = 0.f;

  for (int it = 0; it <= TSEQ + 2; ++it) {
    const bool l1 = (it < TSEQ);
    const bool l2 = (it >= 3);          // processes t2 = it-3
    const int  t2 = it - 3;

    // ---- pre-poll loads (deps confirmed by LAST round's poll) ----
    float4 xa, xb;
    if (l1) {
      const int row = tid >> 4, kc = tid & 15;
      const float* xp = x + ((size_t)(cb + row) * TSEQ + it) * DIN + kc * 8;
      xa = *(const float4*)xp; xb = *(const float4*)(xp + 4);
    }
    u64 o1t[8];
    if (l2) {   // out1_{it-3} from ring slot (it-3)&3 (flag>=it-1 known)
      const unsigned short* o1r =
          buf1 + (size_t)(((t2 & 3) * NCL + cluster) * BB) * HDIM;
      #pragma unroll
      for (int ci = 0; ci < 4; ++ci) {
        const int g = ci * 256 + tid, row = g >> 6, kc = g & 63;
        const u64* s = (const u64*)(o1r + (size_t)row * HDIM + kc * 8);
        o1t[2 * ci]     = __hip_atomic_load(s,     __ATOMIC_RELAXED, SCOPE_AGENT);
        o1t[2 * ci + 1] = __hip_atomic_load(s + 1, __ATOMIC_RELAXED, SCOPE_AGENT);
      }
    }

    // ---- poll: single target flag >= it (covers h1_{it-1} and h2_{it-4}) ----
    if (it > 0) {
      if (kq == 0) {
        const unsigned* fl = flag + (lane & 31);
        const unsigned tgt = (unsigned)it;
        while (true) {
          unsigned v = __hip_atomic_load(fl, __ATOMIC_RELAXED, SCOPE_AGENT);
          if (__all((int)(v >= tgt))) break;
          __builtin_amdgcn_s_sleep(1);
        }
      }
      __syncthreads();   // #1
    }

    // ---- stage slabs into swizzled LDS ----
    if (l1) {
      const int row = tid >> 4, kc = tid & 15;
      *(short8*)(&xs[SWZ(row, row * DIN + kc * 8)]) = pack8(xa, xb);
    }
    if (l2) {
      #pragma unroll
      for (int ci = 0; ci < 4; ++ci) {
        const int g = ci * 256 + tid, row = g >> 6, kc = g & 63;
        *(short8*)(&o1s[SWZ(row, row * HDIM + kc * 8)]) =
            mk8(o1t[2 * ci], o1t[2 * ci + 1]);
      }
    }
    {
      u64 h1t[8], h2t[8];
      const unsigned short* h1r =
          buf1 + (size_t)((((it + 3) & 3) * NCL + cluster) * BB) * HDIM;  // slot (it-1)&3
      const unsigned short* h2r =
          buf2 + (size_t)(((it & 1) * NCL + cluster) * BB) * HDIM;        // slot (it-4)&1
      if (l1) {
        #pragma unroll
        for (int ci = 0; ci < 4; ++ci) {
          const int g = ci * 256 + tid, row = g >> 6, kc = g & 63;
          const u64* s = (const u64*)(h1r + (size_t)row * HDIM + kc * 8);
          h1t[2 * ci]     = __hip_atomic_load(s,     __ATOMIC_RELAXED, SCOPE_AGENT);
          h1t[2 * ci + 1] = __hip_atomic_load(s + 1, __ATOMIC_RELAXED, SCOPE_AGENT);
        }
      }
      if (l2) {
        #pragma unroll
        for (int ci = 0; ci < 4; ++ci) {
          const int g = ci * 256 + tid, row = g >> 6, kc = g & 63;
          const u64* s = (const u64*)(h2r + (size_t)row * HDIM + kc * 8);
          h2t[2 * ci]     = __hip_atomic_load(s,     __ATOMIC_RELAXED, SCOPE_AGENT);
          h2t[2 * ci + 1] = __hip_atomic_load(s + 1, __ATOMIC_RELAXED, SCOPE_AGENT);
        }
      }
      if (l1) {
        #pragma unroll
        for (int ci = 0; ci < 4; ++ci) {
          const int g = ci * 256 + tid, row = g >> 6, kc = g & 63;
          *(short8*)(&h1s[SWZ(row, row * HDIM + kc * 8)]) =
              mk8(h1t[2 * ci], h1t[2 * ci + 1]);
        }
      }
      if (l2) {
        #pragma unroll
        for (int ci = 0; ci < 4; ++ci) {
          const int g = ci * 256 + tid, row = g >> 6, kc = g & 63;
          *(short8*)(&h2s[SWZ(row, row * HDIM + kc * 8)]) =
              mk8(h2t[2 * ci], h2t[2 * ci + 1]);
        }
      }
    }
    __syncthreads();   // #2: slabs ready

    // ---- MFMA both layers; write both reds; ONE barrier ----
    if (l1) {
      f32x4 z = {0.f, 0.f, 0.f, 0.f};
      f32x4 acc1[4] = {z, z, z, z};
      #pragma unroll
      for (int sl = 0; sl < 5; ++sl) {
        const int s = kq * 5 + sl;       // K = [x(4) | h1(16)] K-steps
        short8 a;
        if (s < 4)   // only kq==0
          a = *(const short8*)(&xs[SWZ(lm, lm * DIN + s * 32 + 8 * lq)]);
        else
          a = *(const short8*)(&h1s[SWZ(lm, lm * HDIM + (s - 4) * 32 + 8 * lq)]);
        #pragma unroll
        for (int g = 0; g < 4; ++g) acc1[g] = mfma16(a, wf1[g][sl], acc1[g]);
      }
      #pragma unroll
      for (int g = 0; g < 4; ++g)
        #pragma unroll
        for (int r = 0; r < 4; ++r)
          red1[(kq * 16 + lq * 4 + r) * 66 + g * 16 + lm] = acc1[g][r];
    }
    if (l2) {
      f32x4 z = {0.f, 0.f, 0.f, 0.f};
      f32x4 acc2[4] = {z, z, z, z};
      #pragma unroll
      for (int sl = 0; sl < 8; ++sl) {
        const int s2 = kq * 8 + sl;      // K = [out1(16) | h2(16)] K-steps
        short8 a;
        if (s2 < 16)
          a = *(const short8*)(&o1s[SWZ(lm, lm * HDIM + s2 * 32 + 8 * lq)]);
        else
          a = *(const short8*)(&h2s[SWZ(lm, lm * HDIM + (s2 - 16) * 32 + 8 * lq)]);
        #pragma unroll
        for (int g = 0; g < 4; ++g) acc2[g] = mfma16(a, wf2[g][sl], acc2[g]);
      }
      #pragma unroll
      for (int g = 0; g < 4; ++g)
        #pragma unroll
        for (int r = 0; r < 4; ++r)
          red2[(kq * 16 + lq * 4 + r) * 66 + g * 16 + lm] = acc2[g][r];
    }
    __syncthreads();   // #3: reds complete

    // ---- pickups -> pub LDS (final round -> out directly) ----
    if (l1) {
      float p[4];
      #pragma unroll
      for (int g = 0; g < 4; ++g) {
        float v = bias1s[g * 16 + pnn];
        #pragma unroll
        for (int q = 0; q < 4; ++q) v += red1[(q * 16 + pm) * 66 + g * 16 + pnn];
        p[g] = v;
      }
      const float i_ = sigf(p[0]), f_ = sigf(p[1]);
      const float g_ = tanh_(p[2]), o_ = sigf(p[3]);
      c1 = f_ * c1 + i_ * g_;
      pub1s[pm * 16 + pnn] = f2bf(o_ * tanh_(c1));
    }
    if (l2) {
      float p[4];
      #pragma unroll
      for (int g = 0; g < 4; ++g) {
        float v = bias2s[g * 16 + pnn];
        #pragma unroll
        for (int q = 0; q < 4; ++q) v += red2[(q * 16 + pm) * 66 + g * 16 + pnn];
        p[g] = v;
      }
      const float i_ = sigf(p[0]), f_ = sigf(p[1]);
      const float g_ = tanh_(p[2]), o_ = sigf(p[3]);
      c2 = f_ * c2 + i_ * g_;
      const float h2v = o_ * tanh_(c2);
      if (t2 < TSEQ - 1) {
        pub2s[pm * 16 + pnn] = f2bf(h2v);
      } else {                            // final states (t2 = 511)
        const int b = cb + pm;
        out[(size_t)b * HDIM + j * COLS + pnn] = h2v;
        out[(size_t)128 * HDIM + (size_t)b * HDIM + j * COLS + pnn] = c2;
      }
    }
    __syncthreads();   // #4: pub buffers ready

    // ---- wave 0: coalesced publish (8B stores) + wave-local drain + flag ----
    if (kq == 0) {
      const int row = lane >> 2, part = lane & 3;   // 64 lanes cover 16x4 u64
      if (l1) {
        const u64 v = *(const u64*)&pub1s[row * 16 + part * 4];
        unsigned short* wp =
            buf1 + (size_t)(((it & 3) * NCL + cluster) * BB) * HDIM;  // slot it&3
        __hip_atomic_store((u64*)&wp[(size_t)row * HDIM + j * COLS + part * 4],
                           v, __ATOMIC_RELAXED, SCOPE_AGENT);
      }
      if (l2 && t2 < TSEQ - 1) {
        const u64 v = *(const u64*)&pub2s[row * 16 + part * 4];
        unsigned short* wp =
            buf2 + (size_t)(((t2 & 1) * NCL + cluster) * BB) * HDIM;  // slot (it-3)&1
        __hip_atomic_store((u64*)&wp[(size_t)row * HDIM + j * COLS + part * 4],
                           v, __ATOMIC_RELAXED, SCOPE_AGENT);
      }
      asm volatile("s_waitcnt vmcnt(0)" ::: "memory");   // acks complete
      if (lane == 0 && it <= TSEQ + 1)
        __hip_atomic_store(flag + j, (unsigned)(it + 1),
                           __ATOMIC_RELAXED, SCOPE_AGENT);
    }
    // no barrier: next round's #1 rejoins; waves 1-3 prefetch x/o1 meanwhile
  }
}

extern "C" void kernel_launch(void* const* d_in, const int* in_sizes, int n_in,
                              void* d_out, int out_size, void* d_ws, size_t ws_size,
                              hipStream_t stream) {
  const float* x    = (const float*)d_in[0];
  const float* Wih1 = (const float*)d_in[1];
  const float* Whh1 = (const float*)d_in[2];
  const float* bih1 = (const float*)d_in[3];
  const float* bhh1 = (const float*)d_in[4];
  const float* Wih2 = (const float*)d_in[5];
  const float* Whh2 = (const float*)d_in[6];
  const float* bih2 = (const float*)d_in[7];
  const float* bhh2 = (const float*)d_in[8];
  float* out = (float*)d_out;

  const size_t buf1Elems = (size_t)4 * NCL * BB * HDIM;   // 262144 ushorts
  const size_t buf2Elems = (size_t)2 * NCL * BB * HDIM;   // 131072 ushorts
  unsigned short* buf1 = (unsigned short*)d_ws;
  unsigned short* buf2 = buf1 + buf1Elems;
  unsigned* flags = (unsigned*)(buf2 + buf2Elems);

  const int nzero = (int)(((buf1Elems + buf2Elems) * 2 + NCL * 32 * 4) / 4);
  zero_ws<<<(nzero + 255) / 256, 256, 0, stream>>>((unsigned*)d_ws, nzero);
  lstm_persist<<<256, 256, 0, stream>>>(x, Wih1, Whh1, bih1, bhh1,
                                        Wih2, Whh2, bih2, bhh2,
                                        out, buf1, buf2, flags);
}

// Round 13
// 1892.495 us; speedup vs baseline: 3.8905x; 1.2411x over previous
//
#include <hip/hip_runtime.h>
#include <stdint.h>
#include <stddef.h>

// Persistent 2-layer LSTM, V13: V6 structure + per-producer fused poll+load.
// Staging is remapped so wave w stages the columns of producers 8w..8w+7 and
// each THREAD's chunks come from exactly ONE producer: the thread polls that
// producer's flagA/flagB pair, then immediately issues its h1+h2 loads.
// A wave thus starts loading as soon as ITS 8 producers are ready - the
// straggler's detect overlaps the other waves' data loads, and the separate
// post-poll barrier disappears (4 barriers/round, was 5).
// Also: x pre-loaded to regs before the poll; red stride 66->68 (write-
// conflict-free). Everything else (split flags, scattered publishes, drains,
// lag-1 L2, occpad 1-block/CU) is V6-verbatim.
// B=128,T=512,D=128,H=512. 8 clusters x 32 blocks; block owns 16 h-cols of
// both layers; 4 waves = 4 K-quarters.

typedef __attribute__((ext_vector_type(8))) short short8;
typedef __attribute__((ext_vector_type(4))) float f32x4;
typedef unsigned long long u64;

#define DEV static __device__ __forceinline__
#define SCOPE_AGENT __HIP_MEMORY_SCOPE_AGENT

constexpr int TSEQ = 512;
constexpr int DIN  = 128;
constexpr int HDIM = 512;
constexpr int NCL  = 8;    // clusters (bid&7; perf-only placement heuristic)
constexpr int BB   = 16;   // batch rows per cluster
constexpr int NJ   = 32;   // blocks per cluster
constexpr int COLS = 16;   // h-cols per block

DEV unsigned short f2bf(float f) {
  unsigned u = __float_as_uint(f);
  u += 0x7fffu + ((u >> 16) & 1u);   // RNE
  return (unsigned short)(u >> 16);
}
DEV short8 pack8(float4 a, float4 b) {
  short8 r;
  r[0] = (short)f2bf(a.x); r[1] = (short)f2bf(a.y);
  r[2] = (short)f2bf(a.z); r[3] = (short)f2bf(a.w);
  r[4] = (short)f2bf(b.x); r[5] = (short)f2bf(b.y);
  r[6] = (short)f2bf(b.z); r[7] = (short)f2bf(b.w);
  return r;
}
DEV short8 mk8(u64 lo, u64 hi) {
  union { u64 q[2]; short8 v; } u;
  u.q[0] = lo; u.q[1] = hi; return u.v;
}
DEV f32x4 mfma16(short8 a, short8 b, f32x4 c) {
  return __builtin_amdgcn_mfma_f32_16x16x32_bf16(a, b, c, 0, 0, 0);
}
DEV float sigf(float v) { return 1.f / (1.f + __expf(-v)); }
DEV float tanh_(float v) {
  v = fminf(20.f, fmaxf(-20.f, v));
  float e = __expf(2.f * v);
  return (e - 1.f) / (e + 1.f);
}

__global__ void zero_ws(unsigned* p, int n) {
  int i = blockIdx.x * 256 + threadIdx.x;
  if (i < n)
    __hip_atomic_store(p + i, 0u, __ATOMIC_RELAXED, SCOPE_AGENT);
}

// LDS slab swizzle on short-index: byte ^ ((row&15)<<4)
#define SWZ(row, idx) ((idx) ^ (((row) & 15) << 3))

__global__ __launch_bounds__(256, 1) void lstm_persist(
    const float* __restrict__ x,
    const float* __restrict__ Wih1, const float* __restrict__ Whh1,
    const float* __restrict__ bih1, const float* __restrict__ bhh1,
    const float* __restrict__ Wih2, const float* __restrict__ Whh2,
    const float* __restrict__ bih2, const float* __restrict__ bhh2,
    float* __restrict__ out,
    unsigned short* __restrict__ buf1,   // [2][NCL][BB][HDIM] bf16 (h1/out1)
    unsigned short* __restrict__ buf2,   // [2][NCL][BB][HDIM] bf16 (h2)
    unsigned* __restrict__ flags)        // [NCL][64]: A flags 0..31, B 32..63
{
  __shared__ short xs [16 * DIN];    // 4KB  x_t (bf16, swizzled)
  __shared__ short h1s[16 * HDIM];   // 16KB h1_{it-1} (also o1 for L2)
  __shared__ short h2s[16 * HDIM];   // 16KB h2_{it-2}
  __shared__ float red1[4 * 16 * 68];
  __shared__ float red2[4 * 16 * 68];
  __shared__ float bias1s[64], bias2s[64];
  __shared__ float occpad[3072];     // 12KB pad -> ~83KB total -> 1 block/CU

  const int tid  = threadIdx.x;
  const int lane = tid & 63;
  const int lm   = lane & 15;   // A row (batch row) / C col index
  const int lq   = lane >> 4;   // k-octet / C row group
  const int kq   = tid >> 6;    // wave = K-quarter

  const int bid     = blockIdx.x;
  const int cluster = bid & 7;
  const int j       = bid >> 3;       // 0..31 col-group within cluster
  const int cb      = cluster * BB;   // global batch base
  unsigned* flagA = flags + cluster * 64;        // flagA=k+1 after round k L1
  unsigned* flagB = flags + cluster * 64 + NJ;   // flagB=k  after round k L2

  // keep occpad allocated (write-only LDS gets DCE'd)
  asm volatile("" :: "v"(&occpad[tid & 1023]));

  // ---- persistent register weights: B-fragments, n = lane&15 -> gate row ----
  short8 wf1[4][5];   // layer1: K=640 -> 20 K-steps, 5 per wave, x4 gates
  short8 wf2[4][8];   // layer2: K=1024 -> 32 K-steps, 8 per wave, x4 gates
  #pragma unroll
  for (int g = 0; g < 4; ++g) {
    const int gr = g * HDIM + j * COLS + lm;
    #pragma unroll
    for (int sl = 0; sl < 5; ++sl) {
      const int k0 = (kq * 5 + sl) * 32 + 8 * lq;          // 0..639
      const float* src = (k0 < DIN) ? (Wih1 + (size_t)gr * DIN + k0)
                                    : (Whh1 + (size_t)gr * HDIM + (k0 - DIN));
      wf1[g][sl] = pack8(*(const float4*)src, *(const float4*)(src + 4));
    }
    #pragma unroll
    for (int sl = 0; sl < 8; ++sl) {
      const int k0 = (kq * 8 + sl) * 32 + 8 * lq;          // 0..1023
      const float* src = (k0 < HDIM) ? (Wih2 + (size_t)gr * HDIM + k0)
                                     : (Whh2 + (size_t)gr * HDIM + (k0 - HDIM));
      wf2[g][sl] = pack8(*(const float4*)src, *(const float4*)(src + 4));
    }
  }
  if (tid < 64) {
    const int g = tid >> 4, nn = tid & 15;
    const int gr = g * HDIM + j * COLS + nn;
    bias1s[tid] = bih1[gr] + bhh1[gr];
    bias2s[tid] = bih2[gr] + bhh2[gr];
  }

  // pickup: thread = (batch row pm, col pnn); owns c1,c2 across all steps
  const int pm = tid >> 4, pnn = tid & 15;
  float c1 = 0.f, c2 = 0.f;

  // staging map: wave kq owns producers 8*kq .. 8*kq+7.
  // thread covers rows {lr, lr+4, lr+8, lr+12} x cols [skc*8, skc*8+8)
  const int lr   = lane >> 4;              // 0..3 base row
  const int skc  = kq * 16 + (lane & 15);  // 0..63 col granule
  const int prod = skc >> 1;               // the ONE producer of these cols

  for (int it = 0; it <= TSEQ; ++it) {
    const bool l1 = (it < TSEQ);
    const bool l2 = (it >= 1);

    // ---- x pre-load (read-only input; no dependency on peers) ----
    float4 xa, xb;
    if (l1) {
      const int row = tid >> 4, kc16 = tid & 15;
      const float* xp = x + ((size_t)(cb + row) * TSEQ + it) * DIN + kc16 * 8;
      xa = *(const float4*)xp; xb = *(const float4*)(xp + 4);
    }

    // ---- fused per-producer poll + slab loads + LDS writes ----
    const unsigned short* h1r =
        buf1 + (size_t)(((it + 1) & 1) * NCL + cluster) * BB * HDIM;  // h1_{it-1}
    const unsigned short* h2r =
        buf2 + (size_t)((it & 1) * NCL + cluster) * BB * HDIM;        // h2_{it-2}
    if (it > 0) {
      const unsigned tgA = (unsigned)(it < TSEQ ? it : TSEQ);
      const unsigned tgB = (unsigned)(it - 1);
      const unsigned* fA = flagA + prod;
      const unsigned* fB = flagB + prod;
      while (true) {
        unsigned a = __hip_atomic_load(fA, __ATOMIC_RELAXED, SCOPE_AGENT);
        unsigned b = __hip_atomic_load(fB, __ATOMIC_RELAXED, SCOPE_AGENT);
        if (a >= tgA && b >= tgB) break;
        __builtin_amdgcn_s_sleep(1);
      }
    }
    {
      u64 t1[8], t2[8];
      #pragma unroll
      for (int ci = 0; ci < 4; ++ci) {
        const int row = ci * 4 + lr;
        const u64* s = (const u64*)(h1r + (size_t)row * HDIM + skc * 8);
        t1[2 * ci]     = __hip_atomic_load(s,     __ATOMIC_RELAXED, SCOPE_AGENT);
        t1[2 * ci + 1] = __hip_atomic_load(s + 1, __ATOMIC_RELAXED, SCOPE_AGENT);
      }
      #pragma unroll
      for (int ci = 0; ci < 4; ++ci) {
        const int row = ci * 4 + lr;
        const u64* s = (const u64*)(h2r + (size_t)row * HDIM + skc * 8);
        t2[2 * ci]     = __hip_atomic_load(s,     __ATOMIC_RELAXED, SCOPE_AGENT);
        t2[2 * ci + 1] = __hip_atomic_load(s + 1, __ATOMIC_RELAXED, SCOPE_AGENT);
      }
      #pragma unroll
      for (int ci = 0; ci < 4; ++ci) {
        const int row = ci * 4 + lr;
        *(short8*)(&h1s[SWZ(row, row * HDIM + skc * 8)]) =
            mk8(t1[2 * ci], t1[2 * ci + 1]);
      }
      #pragma unroll
      for (int ci = 0; ci < 4; ++ci) {
        const int row = ci * 4 + lr;
        *(short8*)(&h2s[SWZ(row, row * HDIM + skc * 8)]) =
            mk8(t2[2 * ci], t2[2 * ci + 1]);
      }
    }
    if (l1) {
      const int row = tid >> 4, kc16 = tid & 15;
      *(short8*)(&xs[SWZ(row, row * DIN + kc16 * 8)]) = pack8(xa, xb);
    }
    __syncthreads();   // #1: slabs ready

    // ---- MFMA: wave kq does its K-quarter, all 4 gate N-tiles ----
    f32x4 z = {0.f, 0.f, 0.f, 0.f};
    f32x4 acc1[4] = {z, z, z, z};
    f32x4 acc2[4] = {z, z, z, z};
    if (l1) {
      #pragma unroll
      for (int sl = 0; sl < 5; ++sl) {
        const int s = kq * 5 + sl;       // K = [x(4) | h1(16)] K-steps
        short8 a;
        if (s < 4)   // only kq==0
          a = *(const short8*)(&xs[SWZ(lm, lm * DIN + s * 32 + 8 * lq)]);
        else
          a = *(const short8*)(&h1s[SWZ(lm, lm * HDIM + (s - 4) * 32 + 8 * lq)]);
        #pragma unroll
        for (int g = 0; g < 4; ++g) acc1[g] = mfma16(a, wf1[g][sl], acc1[g]);
      }
    }
    if (l2) {
      #pragma unroll
      for (int sl = 0; sl < 8; ++sl) {
        const int s2 = kq * 8 + sl;      // K = [out1(16) | h2(16)] K-steps
        short8 a;
        if (s2 < 16)
          a = *(const short8*)(&h1s[SWZ(lm, lm * HDIM + s2 * 32 + 8 * lq)]);
        else
          a = *(const short8*)(&h2s[SWZ(lm, lm * HDIM + (s2 - 16) * 32 + 8 * lq)]);
        #pragma unroll
        for (int g = 0; g < 4; ++g) acc2[g] = mfma16(a, wf2[g][sl], acc2[g]);
      }
    }
    // C layout: col = lane&15 (gate row), row = lq*4+r (batch row)
    if (l1) {
      #pragma unroll
      for (int g = 0; g < 4; ++g)
        #pragma unroll
        for (int r = 0; r < 4; ++r)
          red1[(kq * 16 + lq * 4 + r) * 68 + g * 16 + lm] = acc1[g][r];
    }
    if (l2) {
      #pragma unroll
      for (int g = 0; g < 4; ++g)
        #pragma unroll
        for (int r = 0; r < 4; ++r)
          red2[(kq * 16 + lq * 4 + r) * 68 + g * 16 + lm] = acc2[g][r];
    }
    __syncthreads();   // #2: reds complete

    // ---- layer-1 pickup + publish + flagA (h1 recurrence critical path) ----
    if (l1) {
      float p[4];
      #pragma unroll
      for (int g = 0; g < 4; ++g) {
        float v = bias1s[g * 16 + pnn];
        #pragma unroll
        for (int q = 0; q < 4; ++q) v += red1[(q * 16 + pm) * 68 + g * 16 + pnn];
        p[g] = v;
      }
      const float i_ = sigf(p[0]), f_ = sigf(p[1]);
      const float g_ = tanh_(p[2]), o_ = sigf(p[3]);
      c1 = f_ * c1 + i_ * g_;
      const float h1v = o_ * tanh_(c1);
      unsigned short* wp = buf1 + (size_t)((it & 1) * NCL + cluster) * BB * HDIM;
      __hip_atomic_store(&wp[pm * HDIM + j * COLS + pnn], f2bf(h1v),
                         __ATOMIC_RELAXED, SCOPE_AGENT);
    }
    __syncthreads();   // #3: drains vmcnt, h1 publishes complete
    if (tid == 0 && l1)
      __hip_atomic_store(flagA + j, (unsigned)(it + 1),
                         __ATOMIC_RELAXED, SCOPE_AGENT);

    // ---- layer-2 pickup + publish + flagB (one step of slack) ----
    if (l2) {
      float p[4];
      #pragma unroll
      for (int g = 0; g < 4; ++g) {
        float v = bias2s[g * 16 + pnn];
        #pragma unroll
        for (int q = 0; q < 4; ++q) v += red2[(q * 16 + pm) * 68 + g * 16 + pnn];
        p[g] = v;
      }
      const float i_ = sigf(p[0]), f_ = sigf(p[1]);
      const float g_ = tanh_(p[2]), o_ = sigf(p[3]);
      c2 = f_ * c2 + i_ * g_;
      const float h2v = o_ * tanh_(c2);
      if (l1) {
        unsigned short* wp =
            buf2 + (size_t)(((it + 1) & 1) * NCL + cluster) * BB * HDIM;
        __hip_atomic_store(&wp[pm * HDIM + j * COLS + pnn], f2bf(h2v),
                           __ATOMIC_RELAXED, SCOPE_AGENT);
      } else {
        const int b = cb + pm;                       // final states (t = 511)
        out[(size_t)b * HDIM + j * COLS + pnn] = h2v;
        out[(size_t)128 * HDIM + (size_t)b * HDIM + j * COLS + pnn] = c2;
      }
    }
    __syncthreads();   // #4: drains vmcnt, h2 publishes complete
    if (tid == 0 && l1 && l2)
      __hip_atomic_store(flagB + j, (unsigned)it,
                         __ATOMIC_RELAXED, SCOPE_AGENT);
  }
}

extern "C" void kernel_launch(void* const* d_in, const int* in_sizes, int n_in,
                              void* d_out, int out_size, void* d_ws, size_t ws_size,
                              hipStream_t stream) {
  const float* x    = (const float*)d_in[0];
  const float* Wih1 = (const float*)d_in[1];
  const float* Whh1 = (const float*)d_in[2];
  const float* bih1 = (const float*)d_in[3];
  const float* bhh1 = (const float*)d_in[4];
  const float* Wih2 = (const float*)d_in[5];
  const float* Whh2 = (const float*)d_in[6];
  const float* bih2 = (const float*)d_in[7];
  const float* bhh2 = (const float*)d_in[8];
  float* out = (float*)d_out;

  const size_t bufElems = (size_t)2 * NCL * BB * HDIM;   // 131072 ushorts each
  unsigned short* buf1 = (unsigned short*)d_ws;
  unsigned short* buf2 = buf1 + bufElems;
  unsigned* flags = (unsigned*)(buf2 + bufElems);

  const int nzero = (int)((bufElems * 2 * 2 + NCL * 64 * 4) / 4);   // u32 words
  zero_ws<<<(nzero + 255) / 256, 256, 0, stream>>>((unsigned*)d_ws, nzero);
  lstm_persist<<<256, 256, 0, stream>>>(x, Wih1, Whh1, bih1, bhh1,
                                        Wih2, Whh2, bih2, bhh2,
                                        out, buf1, buf2, flags);
}